// Round 19
// baseline (72.669 us; speedup 1.0000x reference)
//
#include <hip/hip_runtime.h>

// GGCARAFE: gradient-guided CARAFE upsample, B=8, C=256, H=W=64, K=3, S=2
// R19: SPLIT k_fused -> k_mask + pure-stream k_out (the clean version of the
// R5 split, with everything learned since):
//   - k_mask: Phase A GEMM + softmax, mask -> global via cooperative f4 stores
//   - k_out: NO LDS, NO barriers, 2048 blocks (8/CU), mask row = 9 f4 loads
//     per thread, stores flow continuously (fillBuffer regime: 87% of peak at
//     10% occupancy). Removes the fused kernel's Phase A/B serialization that
//     six single-factor probes (R11/R14-R18) could not touch.
// ws layout (float indices):
//   w1bf  [64][256] bf16        @ 0        (8192 f32-equiv)
//   mean  [B][H][W] f32         @ 8192     (32768)
//   w2b   [48][576] bf16        @ 40960    (13824 f32-equiv)
//   mask  [B][H][W][36] f32     @ 54784    (1179648)
//   comp_p[8][66][66][64] bf16  @ 1234432  (1115136 f32-equiv) zero ring
// total 2,349,568 floats = 9.40 MB

#define W1BF_OFF  0
#define MEAN_OFF  8192
#define W2B_OFF   40960
#define MASK_OFF  54784
#define CPP_OFF   1234432

typedef __attribute__((ext_vector_type(8))) short bf8;            // 8 bf16 = 16B
typedef __attribute__((ext_vector_type(8))) unsigned short us8;   // 16B store
typedef __attribute__((ext_vector_type(4))) float f4;
typedef __attribute__((ext_vector_type(2))) float f2;

static __device__ inline unsigned short f2bf(float f) {
    unsigned u = __float_as_uint(f);
    unsigned r = u + 0x7FFFu + ((u >> 16) & 1u);   // RNE
    return (unsigned short)(r >> 16);
}

// k_init: zero comp_p PAD RING only + weight converts/transposes.
__global__ __launch_bounds__(256) void k_init(const float* __restrict__ w1,
                                              const float* __restrict__ w2,
                                              float* __restrict__ ws) {
    int bid = blockIdx.x, t = threadIdx.x;
    if (bid < 65) {
        int id = bid * 256 + t;           // 0..16639
        if (id < 16640) {
            int px = id >> 3, part = id & 7;
            int b = px / 260, r = px % 260;
            int y, xx;
            if (r < 66)       { y = 0;  xx = r; }
            else if (r < 132) { y = 65; xx = r - 66; }
            else              { int s = r - 132; y = (s & 63) + 1; xx = (s >> 6) ? 65 : 0; }
            uint4* p = (uint4*)((unsigned short*)(ws + CPP_OFF)
                                + ((size_t)(b * 66 + y) * 66 + xx) * 64) + part;
            *p = uint4{0, 0, 0, 0};
        }
        return;
    }
    unsigned short* w1bf = (unsigned short*)(ws + W1BF_OFF);
    unsigned short* w2b  = (unsigned short*)(ws + W2B_OFF);
    int gid = (bid - 65) * 256 + t;
    int stride = 68 * 256;
    for (int i = gid; i < 64 * 256; i += stride)         // direct convert
        w1bf[i] = f2bf(w1[i]);
    for (int i = gid; i < 48 * 576; i += stride) {       // w2b[o][s*64+j]
        int o = i / 576, k = i % 576;
        int s = k >> 6, j = k & 63;
        w2b[i] = (o < 36) ? f2bf(w2[o * 576 + j * 9 + s]) : (unsigned short)0;
    }
}

// comp GEMM (R13 structure, batch->XCD swizzle): grid 512; block 256 = 4 waves.
__global__ __launch_bounds__(256) void k_comp(const float* __restrict__ x,
                                              const float* __restrict__ b1,
                                              float* __restrict__ ws) {
    const unsigned short* w1bf = (const unsigned short*)(ws + W1BF_OFF);
    float* mean = ws + MEAN_OFF;
    unsigned short* cpp = (unsigned short*)(ws + CPP_OFF);
    __shared__ unsigned short xbf[64][260];   // 33.3 KB (+4 pad)
    __shared__ float msp[16][64];             // 4 KB mean partials
    __shared__ float ctile[64][68];           // 17.4 KB epilogue staging

    int bid = blockIdx.x;
    int swz = (bid & 7) * 64 + (bid >> 3);    // batch b -> XCD b
    int b = swz >> 6, h = swz & 63;
    int t = threadIdx.x;

    int cg = t >> 4;
    int px4 = (t & 15) * 4;
    float ms0 = 0.f, ms1 = 0.f, ms2 = 0.f, ms3 = 0.f;
    const float* xb = x + (size_t)b * 256 * 4096 + h * 64;
#pragma unroll
    for (int it = 0; it < 16; it++) {
        int c = it * 16 + cg;
        f4 v = *(const f4*)(xb + (size_t)c * 4096 + px4);
        ms0 += v[0]; ms1 += v[1]; ms2 += v[2]; ms3 += v[3];
        xbf[px4 + 0][c] = f2bf(v[0]);
        xbf[px4 + 1][c] = f2bf(v[1]);
        xbf[px4 + 2][c] = f2bf(v[2]);
        xbf[px4 + 3][c] = f2bf(v[3]);
    }
    msp[cg][px4 + 0] = ms0; msp[cg][px4 + 1] = ms1;
    msp[cg][px4 + 2] = ms2; msp[cg][px4 + 3] = ms3;
    __syncthreads();
    if (t < 64) {
        float s = 0.f;
#pragma unroll
        for (int k2 = 0; k2 < 16; k2++) s += msp[k2][t];
        mean[(b * 64 + h) * 64 + t] = s * (1.f / 256.f);
    }

    int wid = __builtin_amdgcn_readfirstlane(t >> 6);  // 0..3
    int l = t & 63, lm = l & 15, lk = l >> 4;
    bf8 bfrag[8];
    const unsigned short* wp = w1bf + (size_t)(wid * 16 + lm) * 256 + lk * 8;
#pragma unroll
    for (int ks = 0; ks < 8; ks++) bfrag[ks] = *(const bf8*)(wp + ks * 32);
    float bb = b1[wid * 16 + lm];
#pragma unroll
    for (int mt = 0; mt < 4; mt++) {
        f4 acc = {bb, bb, bb, bb};
#pragma unroll
        for (int ks = 0; ks < 8; ks++) {
            bf8 af = *(const bf8*)(&xbf[mt * 16 + lm][ks * 32 + lk * 8]);
            acc = __builtin_amdgcn_mfma_f32_16x16x32_bf16(af, bfrag[ks], acc, 0, 0, 0);
        }
#pragma unroll
        for (int r = 0; r < 4; r++)
            ctile[mt * 16 + lk * 4 + r][wid * 16 + lm] = acc[r];   // C[m][n]
    }
    __syncthreads();

    int px = t >> 2, jq = t & 3;
    us8 o0, o1;
#pragma unroll
    for (int i = 0; i < 8; i++) {
        o0[i] = f2bf(ctile[px][jq * 16 + i]);
        o1[i] = f2bf(ctile[px][jq * 16 + 8 + i]);
    }
    unsigned short* dst = cpp + ((size_t)(b * 66 + h + 1) * 66 + (px + 1)) * 64 + jq * 16;
    *(us8*)dst = o0;
    *(us8*)(dst + 8) = o1;
}

// k_mask: Phase A GEMM + grad/softmax; mask -> global, cooperative f4 stores.
// grid 512 = (b,h) swizzled (batch b -> XCD b); block 384 = 6 waves.
__global__ __launch_bounds__(384) void k_mask(const float* __restrict__ b2,
                                              float* __restrict__ ws) {
    const unsigned short* w2b = (const unsigned short*)(ws + W2B_OFF);
    const unsigned short* cpp = (const unsigned short*)(ws + CPP_OFF);
    const float* mean = ws + MEAN_OFF;
    float* mask = ws + MASK_OFF;
    __shared__ float kern[64][49];
    __shared__ float msk2[64 * 36];   // packed for f4 cooperative store

    int bid = blockIdx.x;
    int swz = (bid & 7) * 64 + (bid >> 3);             // batch b -> XCD b
    int b = swz >> 6, h = swz & 63;
    int t = threadIdx.x;
    int wid = __builtin_amdgcn_readfirstlane(t >> 6);  // 0..5
    int l = t & 63;

    // ---- Phase A: kern GEMM (M=64 px, N=48, K=576) ----
    {
        int o = wid % 3, ph = wid / 3;
        int lm = l & 15, lk = l >> 4;
        bf8 bfrag[18];
        const unsigned short* bp = w2b + (size_t)(o * 16 + lm) * 576 + lk * 8;
#pragma unroll
        for (int ks = 0; ks < 18; ks++) bfrag[ks] = *(const bf8*)(bp + ks * 32);

        const unsigned short* abase = cpp + ((size_t)(b * 66 + h) * 66 + lm) * 64 + lk * 8;
#pragma unroll
        for (int hf = 0; hf < 2; hf++) {
            int w0 = (ph * 2 + hf) * 16;
            const unsigned short* ab = abase + w0 * 64;
            f4 acc = {0.f, 0.f, 0.f, 0.f};
#pragma unroll
            for (int ks = 0; ks < 18; ks++) {
                const int s = ks >> 1, jh = ks & 1;
                const int dy = s / 3, dx = s % 3;
                bf8 af = *(const bf8*)(ab + (dy * 66 + dx) * 64 + jh * 32);
                acc = __builtin_amdgcn_mfma_f32_16x16x32_bf16(af, bfrag[ks], acc, 0, 0, 0);
            }
#pragma unroll
            for (int r = 0; r < 4; r++)
                kern[w0 + lk * 4 + r][o * 16 + lm] = acc[r];
        }
    }
    __syncthreads();

    // grad guidance + softmax -> msk2 (packed); thread (w, pq) for t < 256
    if (t < 256) {
        int w = t & 63, pq = t >> 6;
        float mc = mean[(b * 64 + h) * 64 + w];
        float v[9], mx = -1e30f;
#pragma unroll
        for (int kk = 0; kk < 9; kk++) {
            int y = h + kk / 3 - 1, xw = w + kk % 3 - 1;
            float mv = ((unsigned)y < 64u && (unsigned)xw < 64u)
                           ? mean[(b * 64 + y) * 64 + xw] : 0.f;
            float d = mv - mc;
            float g = 1.f / (d * d + 0.2f);
            v[kk] = g * (kern[w][kk * 4 + pq] + b2[kk * 4 + pq]);
            mx = fmaxf(mx, v[kk]);
        }
        float s = 0.f;
#pragma unroll
        for (int kk = 0; kk < 9; kk++) { v[kk] = __expf(v[kk] - mx); s += v[kk]; }
        float inv = 1.f / s;
#pragma unroll
        for (int kk = 0; kk < 9; kk++) msk2[w * 36 + pq * 9 + kk] = v[kk] * inv;
    }
    __syncthreads();

    // cooperative coalesced f4 store: 64*36 = 2304 f32 = 576 f4
    float* mgbl = mask + (size_t)((b * 64 + h) * 64) * 36;
    for (int i = t; i < 576; i += 384)
        ((f4*)mgbl)[i] = ((const f4*)msk2)[i];
}

// k_out: PURE STREAM. grid 2048 = (b,h,cg) swizzled (batch b -> XCD b);
// block 256 = 64 w x 4 c-slots; no LDS, no barriers; 8 blocks/CU resident.
// Per thread: 9 f4 mask loads once, then 16 c-iters x (9 loads, 36 FMA,
// 2 f2 stores).
__global__ __launch_bounds__(256) void k_out(const float* __restrict__ x,
                                             const float* __restrict__ ws,
                                             float* __restrict__ out) {
    const float* mask = ws + MASK_OFF;
    int bid = blockIdx.x;
    int swz = (bid & 7) * 256 + (bid >> 3);    // 2048 = 8 x 256; b = bid&7
    int b = swz >> 8;
    int rem = swz & 255;
    int h = rem >> 2, cg = rem & 3;
    int t = threadIdx.x;
    int w = t & 63, cs = t >> 6;

    const float* mrow = mask + (size_t)(((b * 64 + h) * 64 + w)) * 36;
    float m[4][9];                    // 9 f4 loads (contiguous 144 B)
#pragma unroll
    for (int pq = 0; pq < 4; pq++)
#pragma unroll
        for (int kk = 0; kk < 9; kk++) m[pq][kk] = mrow[pq * 9 + kk];

    for (int c = cg * 64 + cs; c < cg * 64 + 64; c += 4) {
        const float* xb = x + (size_t)(b * 256 + c) * 4096;
        float p[3][3];
#pragma unroll
        for (int dy = 0; dy < 3; dy++) {
            int y = h + dy - 1;
            bool yok = (unsigned)y < 64u;
#pragma unroll
            for (int dx = 0; dx < 3; dx++) {
                int xx = w + dx - 1;
                p[dy][dx] = (yok && (unsigned)xx < 64u) ? xb[y * 64 + xx] : 0.f;
            }
        }
        float o00 = 0.f, o01 = 0.f, o10 = 0.f, o11 = 0.f;
#pragma unroll
        for (int kk = 0; kk < 9; kk++) {
            float pv = p[kk / 3][kk % 3];
            o00 += pv * m[0][kk];
            o01 += pv * m[1][kk];
            o10 += pv * m[2][kk];
            o11 += pv * m[3][kk];
        }
        float* ob = out + ((size_t)(b * 256 + c) * 128 + 2 * h) * 128 + 2 * w;
        *(f2*)ob = f2{o00, o01};             // row 2h   (p=0)
        *(f2*)(ob + 128) = f2{o10, o11};     // row 2h+1 (p=1)
    }
}

extern "C" void kernel_launch(void* const* d_in, const int* in_sizes, int n_in,
                              void* d_out, int out_size, void* d_ws, size_t ws_size,
                              hipStream_t stream) {
    const float* x  = (const float*)d_in[0];
    const float* w1 = (const float*)d_in[1];
    const float* b1 = (const float*)d_in[2];
    const float* w2 = (const float*)d_in[3];
    const float* b2 = (const float*)d_in[4];
    float* out = (float*)d_out;
    float* ws  = (float*)d_ws;

    k_init<<<133, 256, 0, stream>>>(w1, w2, ws);
    k_comp<<<512, 256, 0, stream>>>(x, b1, ws);
    k_mask<<<512, 384, 0, stream>>>(b2, ws);
    k_out<<<2048, 256, 0, stream>>>(x, ws, out);
}

// Round 20
// 67.188 us; speedup vs baseline: 1.0816x; 1.0816x over previous
//
#include <hip/hip_runtime.h>

// GGCARAFE: gradient-guided CARAFE upsample, B=8, C=256, H=W=64, K=3, S=2
// R20 = R13 VERBATIM (measured best: 67.3 us) — locking in the plateau.
// Ledger: 7 single-factor probes around this structure all null/negative
// (R11 prefetch 87.4, R14 L2/nt 69.7, R15 f4-store 73.3, R16 half-row 68.4,
//  R17 VGPR 68.0, R18 XCD-align 67.7, R19 fission 72.7).
// Budget: comp(MFMA) ~12 + fused(PhaseA ~9 + mixed-stream store phase ~30,
// floor proven by R19 pure-stream k_out) + init/launch ~8 => ~62 us best
// case; 67.3 measured = within ~8% (plateau noise ±1.5).
// ws layout (float indices):
//   w1bf  [64][256] bf16        @ 0       (8192 f32-equiv)
//   mean  [B][H][W] f32         @ 8192    (32768)
//   w2b   [48][576] bf16        @ 40960   (13824 f32-equiv)
//   comp_p[8][66][66][64] bf16  @ 54784   (1115136 f32-equiv) zero ring
// total 1,169,920 floats = 4.68 MB

#define W1BF_OFF  0
#define MEAN_OFF  8192
#define W2B_OFF   40960
#define CPP_OFF   54784

typedef __attribute__((ext_vector_type(8))) short bf8;            // 8 bf16 = 16B
typedef __attribute__((ext_vector_type(8))) unsigned short us8;   // 16B store
typedef __attribute__((ext_vector_type(4))) float f4;
typedef __attribute__((ext_vector_type(2))) float f2;

static __device__ inline unsigned short f2bf(float f) {
    unsigned u = __float_as_uint(f);
    unsigned r = u + 0x7FFFu + ((u >> 16) & 1u);   // RNE
    return (unsigned short)(r >> 16);
}

// k_init: zero comp_p PAD RING only + weight converts/transposes.
__global__ __launch_bounds__(256) void k_init(const float* __restrict__ w1,
                                              const float* __restrict__ w2,
                                              float* __restrict__ ws) {
    int bid = blockIdx.x, t = threadIdx.x;
    if (bid < 65) {
        int id = bid * 256 + t;           // 0..16639
        if (id < 16640) {
            int px = id >> 3, part = id & 7;
            int b = px / 260, r = px % 260;
            int y, xx;
            if (r < 66)       { y = 0;  xx = r; }
            else if (r < 132) { y = 65; xx = r - 66; }
            else              { int s = r - 132; y = (s & 63) + 1; xx = (s >> 6) ? 65 : 0; }
            uint4* p = (uint4*)((unsigned short*)(ws + CPP_OFF)
                                + ((size_t)(b * 66 + y) * 66 + xx) * 64) + part;
            *p = uint4{0, 0, 0, 0};
        }
        return;
    }
    unsigned short* w1bf = (unsigned short*)(ws + W1BF_OFF);
    unsigned short* w2b  = (unsigned short*)(ws + W2B_OFF);
    int gid = (bid - 65) * 256 + t;
    int stride = 68 * 256;
    for (int i = gid; i < 64 * 256; i += stride)         // direct convert
        w1bf[i] = f2bf(w1[i]);
    for (int i = gid; i < 48 * 576; i += stride) {       // w2b[o][s*64+j]
        int o = i / 576, k = i % 576;
        int s = k >> 6, j = k & 63;
        w2b[i] = (o < 36) ? f2bf(w2[o * 576 + j * 9 + s]) : (unsigned short)0;
    }
}

// comp GEMM: grid 512 = (b,h); block 256 = 4 waves.
__global__ __launch_bounds__(256) void k_comp(const float* __restrict__ x,
                                              const float* __restrict__ b1,
                                              float* __restrict__ ws) {
    const unsigned short* w1bf = (const unsigned short*)(ws + W1BF_OFF);
    float* mean = ws + MEAN_OFF;
    unsigned short* cpp = (unsigned short*)(ws + CPP_OFF);
    __shared__ unsigned short xbf[64][260];   // 33.3 KB (+4 pad)
    __shared__ float msp[16][64];             // 4 KB mean partials
    __shared__ float ctile[64][68];           // 17.4 KB epilogue staging

    int bid = blockIdx.x;
    int b = bid >> 6, h = bid & 63;
    int t = threadIdx.x;

    int cg = t >> 4;
    int px4 = (t & 15) * 4;
    float ms0 = 0.f, ms1 = 0.f, ms2 = 0.f, ms3 = 0.f;
    const float* xb = x + (size_t)b * 256 * 4096 + h * 64;
#pragma unroll
    for (int it = 0; it < 16; it++) {
        int c = it * 16 + cg;
        f4 v = *(const f4*)(xb + (size_t)c * 4096 + px4);
        ms0 += v[0]; ms1 += v[1]; ms2 += v[2]; ms3 += v[3];
        xbf[px4 + 0][c] = f2bf(v[0]);
        xbf[px4 + 1][c] = f2bf(v[1]);
        xbf[px4 + 2][c] = f2bf(v[2]);
        xbf[px4 + 3][c] = f2bf(v[3]);
    }
    msp[cg][px4 + 0] = ms0; msp[cg][px4 + 1] = ms1;
    msp[cg][px4 + 2] = ms2; msp[cg][px4 + 3] = ms3;
    __syncthreads();
    if (t < 64) {
        float s = 0.f;
#pragma unroll
        for (int k2 = 0; k2 < 16; k2++) s += msp[k2][t];
        mean[(b * 64 + h) * 64 + t] = s * (1.f / 256.f);
    }

    int wid = __builtin_amdgcn_readfirstlane(t >> 6);  // 0..3
    int l = t & 63, lm = l & 15, lk = l >> 4;
    bf8 bfrag[8];
    const unsigned short* wp = w1bf + (size_t)(wid * 16 + lm) * 256 + lk * 8;
#pragma unroll
    for (int ks = 0; ks < 8; ks++) bfrag[ks] = *(const bf8*)(wp + ks * 32);
    float bb = b1[wid * 16 + lm];
#pragma unroll
    for (int mt = 0; mt < 4; mt++) {
        f4 acc = {bb, bb, bb, bb};
#pragma unroll
        for (int ks = 0; ks < 8; ks++) {
            bf8 af = *(const bf8*)(&xbf[mt * 16 + lm][ks * 32 + lk * 8]);
            acc = __builtin_amdgcn_mfma_f32_16x16x32_bf16(af, bfrag[ks], acc, 0, 0, 0);
        }
#pragma unroll
        for (int r = 0; r < 4; r++)
            ctile[mt * 16 + lk * 4 + r][wid * 16 + lm] = acc[r];   // C[m][n]
    }
    __syncthreads();

    int px = t >> 2, jq = t & 3;
    us8 o0, o1;
#pragma unroll
    for (int i = 0; i < 8; i++) {
        o0[i] = f2bf(ctile[px][jq * 16 + i]);
        o1[i] = f2bf(ctile[px][jq * 16 + 8 + i]);
    }
    unsigned short* dst = cpp + ((size_t)(b * 66 + h + 1) * 66 + (px + 1)) * 64 + jq * 16;
    *(us8*)dst = o0;
    *(us8*)(dst + 8) = o1;
}

// FUSED mask+out. grid 512 = (b,h) swizzled; block 384 = 6 waves.
__global__ __launch_bounds__(384) void k_fused(const float* __restrict__ x,
                                               const float* __restrict__ b2,
                                               const float* __restrict__ ws,
                                               float* __restrict__ out) {
    const unsigned short* w2b = (const unsigned short*)(ws + W2B_OFF);
    const unsigned short* cpp = (const unsigned short*)(ws + CPP_OFF);
    const float* mean = ws + MEAN_OFF;
    __shared__ float kern[64][49];   // stride 49: conflict-free epilogue reads
    __shared__ float msk[64][37];    // stride 37: <=2-way on Phase B hoist

    int bid = blockIdx.x;
    int swz = (bid & 7) * 64 + (bid >> 3);             // XCD chunking, bijective
    int b = swz >> 6, h = swz & 63;
    int t = threadIdx.x;
    int wid = __builtin_amdgcn_readfirstlane(t >> 6);  // 0..5, wave-uniform
    int l = t & 63;

    // ---- Phase A: kern GEMM (M=64 px, N=48, K=576) ----
    {
        int o = wid % 3, ph = wid / 3;
        int lm = l & 15, lk = l >> 4;
        bf8 bfrag[18];
        const unsigned short* bp = w2b + (size_t)(o * 16 + lm) * 576 + lk * 8;
#pragma unroll
        for (int ks = 0; ks < 18; ks++) bfrag[ks] = *(const bf8*)(bp + ks * 32);

        const unsigned short* abase = cpp + ((size_t)(b * 66 + h) * 66 + lm) * 64 + lk * 8;
#pragma unroll
        for (int hf = 0; hf < 2; hf++) {
            int w0 = (ph * 2 + hf) * 16;
            const unsigned short* ab = abase + w0 * 64;
            f4 acc = {0.f, 0.f, 0.f, 0.f};
#pragma unroll
            for (int ks = 0; ks < 18; ks++) {
                const int s = ks >> 1, jh = ks & 1;
                const int dy = s / 3, dx = s % 3;          // compile-time
                bf8 af = *(const bf8*)(ab + (dy * 66 + dx) * 64 + jh * 32);
                acc = __builtin_amdgcn_mfma_f32_16x16x32_bf16(af, bfrag[ks], acc, 0, 0, 0);
            }
#pragma unroll
            for (int r = 0; r < 4; r++)
                kern[w0 + lk * 4 + r][o * 16 + lm] = acc[r];
        }
    }
    __syncthreads();

    // grad guidance + softmax -> msk LDS; thread (w, pq) for t < 256
    if (t < 256) {
        int w = t & 63, pq = t >> 6;
        float mc = mean[(b * 64 + h) * 64 + w];
        float v[9], mx = -1e30f;
#pragma unroll
        for (int kk = 0; kk < 9; kk++) {
            int y = h + kk / 3 - 1, xw = w + kk % 3 - 1;
            float mv = ((unsigned)y < 64u && (unsigned)xw < 64u)
                           ? mean[(b * 64 + y) * 64 + xw] : 0.f;
            float d = mv - mc;
            float g = 1.f / (d * d + 0.2f);
            v[kk] = g * (kern[w][kk * 4 + pq] + b2[kk * 4 + pq]);
            mx = fmaxf(mx, v[kk]);
        }
        float s = 0.f;
#pragma unroll
        for (int kk = 0; kk < 9; kk++) { v[kk] = __expf(v[kk] - mx); s += v[kk]; }
        float inv = 1.f / s;
#pragma unroll
        for (int kk = 0; kk < 9; kk++) msk[w][pq * 9 + kk] = v[kk] * inv;
    }
    __syncthreads();

    // ---- Phase B: reassembly, f2 stores ----
    int wv = t >> 6;                 // 0..5: c-slot
    int w = l;

    float m[4][9];
#pragma unroll
    for (int pq = 0; pq < 4; pq++)
#pragma unroll
        for (int kk = 0; kk < 9; kk++) m[pq][kk] = msk[w][pq * 9 + kk];

    for (int c = wv; c < 256; c += 6) {
        const float* xb = x + (size_t)(b * 256 + c) * 4096;
        float p[3][3];
#pragma unroll
        for (int dy = 0; dy < 3; dy++) {
            int y = h + dy - 1;
            bool yok = (unsigned)y < 64u;
#pragma unroll
            for (int dx = 0; dx < 3; dx++) {
                int xx = w + dx - 1;
                p[dy][dx] = (yok && (unsigned)xx < 64u) ? xb[y * 64 + xx] : 0.f;
            }
        }
        float o00 = 0.f, o01 = 0.f, o10 = 0.f, o11 = 0.f;
#pragma unroll
        for (int kk = 0; kk < 9; kk++) {
            float pv = p[kk / 3][kk % 3];
            o00 += pv * m[0][kk];
            o01 += pv * m[1][kk];
            o10 += pv * m[2][kk];
            o11 += pv * m[3][kk];
        }
        float* ob = out + ((size_t)(b * 256 + c) * 128 + 2 * h) * 128 + 2 * w;
        *(f2*)ob = f2{o00, o01};             // row 2h   (p=0)
        *(f2*)(ob + 128) = f2{o10, o11};     // row 2h+1 (p=1)
    }
}

extern "C" void kernel_launch(void* const* d_in, const int* in_sizes, int n_in,
                              void* d_out, int out_size, void* d_ws, size_t ws_size,
                              hipStream_t stream) {
    const float* x  = (const float*)d_in[0];
    const float* w1 = (const float*)d_in[1];
    const float* b1 = (const float*)d_in[2];
    const float* w2 = (const float*)d_in[3];
    const float* b2 = (const float*)d_in[4];
    float* out = (float*)d_out;
    float* ws  = (float*)d_ws;

    k_init<<<133, 256, 0, stream>>>(w1, w2, ws);
    k_comp<<<512, 256, 0, stream>>>(x, b1, ws);
    k_fused<<<512, 384, 0, stream>>>(x, b2, ws, out);
}